// Round 5
// baseline (211.839 us; speedup 1.0000x reference)
//
#include <hip/hip_runtime.h>
#include <hip/hip_bf16.h>
#include <math.h>

// Problem constants: B=2, L=2048, D=1024, H=16, Hd=64
#define BB 2
#define LL 2048
#define DD 1024
#define NH 16
#define HD 64

typedef short v8s __attribute__((ext_vector_type(8)));   // 8 bf16 (4 VGPRs)
typedef float v4f __attribute__((ext_vector_type(4)));   // 4 fp32 acc
typedef float v16f __attribute__((ext_vector_type(16))); // 16 fp32 acc (32x32)

__device__ __forceinline__ float b2f(unsigned short b) {
  union { unsigned int u; float f; } c; c.u = ((unsigned int)b) << 16; return c.f;
}
__device__ __forceinline__ unsigned short f2b(float x) {
  union { float f; unsigned int u; } c; c.f = x;
  unsigned int u = c.u;
  u += 0x7fffu + ((u >> 16) & 1u);   // RNE
  return (unsigned short)(u >> 16);
}
__device__ __forceinline__ unsigned int asu(float x) {
  union { float f; unsigned int u; } c; c.f = x; return c.u;
}
// pack hi16(lo),hi16(hi) -> one u32 (bf16 RTZ x2) via v_perm_b32
__device__ __forceinline__ unsigned int pk2(float lo, float hi) {
  return __builtin_amdgcn_perm(asu(hi), asu(lo), 0x07060302u);
}

// exp2 (q pre-scaled by 0.125*log2e so softmax uses 2^x)
#if defined(__has_builtin)
#if __has_builtin(__builtin_amdgcn_exp2f)
#define EXP2(x) __builtin_amdgcn_exp2f(x)
#else
#define EXP2(x) __expf((x) * 0.69314718056f)
#endif
#else
#define EXP2(x) __expf((x) * 0.69314718056f)
#endif

// async global->LDS, 16B per lane. LDS dest must be lane-contiguous (m104/m108).
__device__ __forceinline__ void gload16(const void* g, void* l) {
  __builtin_amdgcn_global_load_lds(
      (const __attribute__((address_space(1))) void*)g,
      (__attribute__((address_space(3))) void*)l, 16, 0, 0);
}

// counted vmcnt waits (T4): asm volatile + memory clobber orders all memory
// ops; sched_barrier(0) after pins the schedule (rule #18).
#define VM_WAIT4 do { asm volatile("s_waitcnt vmcnt(4)" ::: "memory"); \
                      __builtin_amdgcn_sched_barrier(0); } while (0)
#define VM_WAIT0 do { asm volatile("s_waitcnt vmcnt(0)" ::: "memory"); \
                      __builtin_amdgcn_sched_barrier(0); } while (0)
#define SBAR     do { __builtin_amdgcn_s_barrier(); \
                      __builtin_amdgcn_sched_barrier(0); } while (0)

// ------ fused cast fp32->bf16 (z=0..15) + RoPE tables (z=16) ---------------
struct CastArgs { const float* s[7]; unsigned short* d[7]; float* ct; float* st; };
__global__ void cast_all(CastArgs a) {
  int z = blockIdx.z;
  if (z == 16) {                            // freqs: 2048*32 entries
    if (blockIdx.x >= 256) return;
    int id = blockIdx.x * blockDim.x + threadIdx.x;
    int t = id >> 5, i = id & 31;
    float inv = powf(10000.0f, -(float)(2 * i) / 64.0f);
    float ang = (float)t * inv;
    a.ct[id] = cosf(ang);
    a.st[id] = sinf(ang);
    return;
  }
  int t = (z < 12) ? (z >> 2) : (z - 9);    // q,k,v get 4 segs; weights 1 each
  int off = (z < 12) ? ((z & 3) << 18) : 0; // 262144 float4-groups per seg
  int i = off + blockIdx.x * blockDim.x + threadIdx.x;
  float4 v = ((const float4*)a.s[t])[i];
  ushort4 o;
  o.x = f2b(v.x); o.y = f2b(v.y); o.z = f2b(v.z); o.w = f2b(v.w);
  ((ushort4*)a.d[t])[i] = o;
}

// -------------- ring-3 GEMM core (128x128 tile, BK=32, counted vmcnt) ------
// LDS: 3 bufs x (A 128x32 + B 128x32) bf16 = 48 KB -> 3 blocks/CU.
// Schedule per iter t: stage tile t+2 (4 gload16) -> compute tile t (8
// ds_read_b128 + 16 MFMA) -> vmcnt(4) [tile t+1 landed, t+2 still IN FLIGHT
// across the barrier] -> s_barrier. Loads never drain to 0 in steady state.
__device__ __forceinline__ size_t ring_src_off(int id, int row0, int Kd) {
  int sr = id >> 3, slot = id & 7;
  int g = slot ^ (sr & 7);
  int r = (sr << 1) | (g >> 2), c = g & 3;
  return (size_t)(row0 + r) * Kd + c * 8;
}
__device__ __forceinline__ int ring_frag_off(int row, int quad) {
  int sr = row >> 1;
  int slot = (((row & 1) << 2) | quad) ^ (sr & 7);
  return sr * 64 + slot * 8;
}

// LDS_ layout: A bufs at [q*4096], B bufs at [12288 + q*4096]  (shorts)
__device__ __forceinline__ void ring_gemm_core(
    const unsigned short* __restrict__ X, const unsigned short* __restrict__ W,
    unsigned short* LDS_, int bm0, int bn0, v4f acc[4][4]) {
  const int K = DD;
  const int tid = threadIdx.x;
  const int lane = tid & 63, wave = tid >> 6;
  const int quad = lane >> 4, l16 = lane & 15;
  const int wm = (wave >> 1) * 64, wn = (wave & 1) * 64;

  // per-thread staging sources (advance by kofs per tile)
  const unsigned short* aS0 = X + ring_src_off(tid, bm0, K);
  const unsigned short* aS1 = X + ring_src_off(256 + tid, bm0, K);
  const unsigned short* bS0 = W + ring_src_off(tid, bn0, K);
  const unsigned short* bS1 = W + ring_src_off(256 + tid, bn0, K);

  // per-lane fragment LDS offsets (shorts)
  int aoff[4], boff[4];
#pragma unroll
  for (int i = 0; i < 4; ++i) {
    aoff[i] = ring_frag_off(wm + i * 16 + l16, quad);
    boff[i] = ring_frag_off(wn + i * 16 + l16, quad);
  }

  auto stage = [&](int q, int kofs) {
    unsigned short* Ab = &LDS_[q * 4096];
    unsigned short* Bb = &LDS_[12288 + q * 4096];
    gload16(aS0 + kofs, &Ab[tid * 8]);
    gload16(aS1 + kofs, &Ab[(256 + tid) * 8]);
    gload16(bS0 + kofs, &Bb[tid * 8]);
    gload16(bS1 + kofs, &Bb[(256 + tid) * 8]);
  };
  auto compute = [&](int q) {
    const unsigned short* Ab = &LDS_[q * 4096];
    const unsigned short* Bb = &LDS_[12288 + q * 4096];
    v8s a[4], b[4];
#pragma unroll
    for (int i = 0; i < 4; ++i) {
      a[i] = *(const v8s*)&Ab[aoff[i]];
      b[i] = *(const v8s*)&Bb[boff[i]];
    }
#pragma unroll
    for (int mi = 0; mi < 4; ++mi)
#pragma unroll
      for (int ni = 0; ni < 4; ++ni)
        acc[mi][ni] = __builtin_amdgcn_mfma_f32_16x16x32_bf16(a[mi], b[ni], acc[mi][ni], 0, 0, 0);
  };

  const int nt = K / 32;   // 32 k-tiles
  stage(0, 0);
  stage(1, 32);
  VM_WAIT4;                // tile 0 landed (tile 1's 4 loads in flight)
  SBAR;
  int cur = 0, s2 = 2, kofs = 64;
#pragma unroll 1
  for (int t = 0; t < nt - 2; ++t) {
    stage(s2, kofs);       // tile t+2 -> 8 outstanding
    compute(cur);          // tile t
    VM_WAIT4;              // tile t+1 landed; t+2 stays in flight
    SBAR;
    cur = (cur == 2) ? 0 : cur + 1;
    s2 = (s2 == 2) ? 0 : s2 + 1;
    kofs += 32;
  }
  compute(cur);            // tile nt-2
  VM_WAIT0;                // tile nt-1 landed
  SBAR;
  cur = (cur == 2) ? 0 : cur + 1;
  compute(cur);            // tile nt-1 (no trailing barrier needed)
}

// ---------------- QKV GEMM with fused RoPE -------------------------------
// z=0 (Q): rope + 0.125*log2e scale fused in epilogue, write qp [B,L,D].
// z=1 (K): rope fused in epilogue, write khh [B,H,L,Hd] directly.
// z=2 (V): transpose in LDS -> vt [B,H,Hd,L_perm].
__global__ __launch_bounds__(256, 3) void gemm_qkv(
    const unsigned short* __restrict__ qb, const unsigned short* __restrict__ kb,
    const unsigned short* __restrict__ vb,
    const unsigned short* __restrict__ wqb, const unsigned short* __restrict__ wkb,
    const unsigned short* __restrict__ wvb,
    const float* __restrict__ bq, const float* __restrict__ bk,
    const float* __restrict__ bv_,
    unsigned short* __restrict__ qp, unsigned short* __restrict__ khh,
    unsigned short* __restrict__ vt,
    const float* __restrict__ ctab, const float* __restrict__ stab) {
  __shared__ __align__(16) unsigned short LDS_[24576];   // 48 KB ring
  const int z = blockIdx.z;
  const unsigned short* X = (z == 0) ? qb : (z == 1) ? kb : vb;
  const unsigned short* W = (z == 0) ? wqb : (z == 1) ? wkb : wvb;
  const float* bias = (z == 0) ? bq : (z == 1) ? bk : bv_;
  const int N = DD;
  const int tid = threadIdx.x;
  const int lane = tid & 63, wave = tid >> 6;
  const int quad = lane >> 4, l16 = lane & 15;
  const int bm0 = blockIdx.x * 128;     // XCD-keyed (id%8 = bm%8)
  const int bn0 = blockIdx.y * 128;
  const int wm = (wave >> 1) * 64, wn = (wave & 1) * 64;

  const v4f vzero = {0.f, 0.f, 0.f, 0.f};
  v4f acc[4][4];
#pragma unroll
  for (int i = 0; i < 4; ++i)
#pragma unroll
    for (int j = 0; j < 4; ++j) acc[i][j] = vzero;

  ring_gemm_core(X, W, LDS_, bm0, bn0, acc);

  float bv[4];
#pragma unroll
  for (int ni = 0; ni < 4; ++ni) bv[ni] = bias[bn0 + wn + ni * 16 + l16];

  if (z < 2) {
    // fused rope epilogue (Q: +softmax scale; K: direct to [B,H,L,Hd])
    const float scl = (z == 0) ? 0.18033688f : 1.0f;  // 0.125*log2(e) for Q
    const int h = (bn0 + wn) >> 6;                    // head (wave-uniform)
    const float sgn = (l16 & 1) ? 1.0f : -1.0f;
#pragma unroll
    for (int mi = 0; mi < 4; ++mi) {
#pragma unroll
      for (int r = 0; r < 4; ++r) {
        int row = bm0 + wm + mi * 16 + quad * 4 + r;
        int l = row & (LL - 1);
        int bidx = row >> 11;
        size_t baseq = (size_t)row * N + bn0 + wn + l16;
        size_t basek = ((size_t)(bidx * NH + h) * LL + l) * HD + l16;
#pragma unroll
        for (int ni = 0; ni < 4; ++ni) {
          int ii = (ni * 16 + l16) >> 1;              // freq index in [0,32)
          float c = ctab[l * 32 + ii], s = stab[l * 32 + ii];
          float v = acc[mi][ni][r] + bv[ni];
          float vp = __shfl_xor(v, 1);
          // even lane: v*c - vp*s ; odd lane: v*c + vp*s
          float o = (v * c + sgn * (vp * s)) * scl;
          if (z == 0) qp[baseq + ni * 16] = f2b(o);
          else        khh[basek + ni * 16] = f2b(o);
        }
      }
    }
  } else {
    // V: transpose in LDS (token bits 2,3 swapped -> flash key permutation),
    // then coalesced store to vt[B,H,Hd,L_perm]. T reuses the ring buffers;
    // barrier first so all waves' last-tile reads are done.
    __syncthreads();
    unsigned short* T = LDS_;          // 128x128 shorts = 32 KB (fits 48)
#pragma unroll
    for (int mi = 0; mi < 4; ++mi)
#pragma unroll
      for (int r = 0; r < 4; ++r) {
        int tl = wm + mi * 16 + quad * 4 + r;                 // token local
        int tlp = (tl & ~12) | ((tl & 4) << 1) | ((tl & 8) >> 1);
        int chunk = tlp >> 3, offw = tlp & 7;
#pragma unroll
        for (int ni = 0; ni < 4; ++ni) {
          int fl = wn + ni * 16 + l16;                        // feature local
          T[fl * 128 + ((chunk ^ (fl & 15)) * 8) + offw] =
              f2b(acc[mi][ni][r] + bv[ni]);
        }
      }
    __syncthreads();
    int fl = tid >> 1, half = tid & 1;
    int fg = bn0 + fl;
    int h2 = fg >> 6, d = fg & 63;
    int bidx = bm0 >> 11, l0 = bm0 & (LL - 1);
    unsigned short* dst =
        vt + (((size_t)(bidx * NH + h2) * HD + d) * LL) + l0 + half * 64;
#pragma unroll
    for (int i = 0; i < 8; ++i) {
      int chunk = half * 8 + i;
      int slot = chunk ^ (fl & 15);
      *(v8s*)(dst + i * 8) = *(const v8s*)&T[fl * 128 + slot * 8];
    }
  }
}

__global__ __launch_bounds__(256, 3) void gemm_out(
    const unsigned short* __restrict__ x, const unsigned short* __restrict__ w,
    const float* __restrict__ b, float* __restrict__ y) {
  __shared__ __align__(16) unsigned short LDS_[24576];   // 48 KB ring
  const int N = DD;
  const int tid = threadIdx.x;
  const int lane = tid & 63, wave = tid >> 6;
  const int quad = lane >> 4, l16 = lane & 15;
  const int bm0 = blockIdx.x * 128;
  const int bn0 = blockIdx.y * 128;
  const int wm = (wave >> 1) * 64, wn = (wave & 1) * 64;

  const v4f vzero = {0.f, 0.f, 0.f, 0.f};
  v4f acc[4][4];
#pragma unroll
  for (int i = 0; i < 4; ++i)
#pragma unroll
    for (int j = 0; j < 4; ++j) acc[i][j] = vzero;

  ring_gemm_core(x, w, LDS_, bm0, bn0, acc);

  float bv[4];
#pragma unroll
  for (int ni = 0; ni < 4; ++ni) bv[ni] = b[bn0 + wn + ni * 16 + l16];
#pragma unroll
  for (int mi = 0; mi < 4; ++mi) {
#pragma unroll
    for (int r = 0; r < 4; ++r) {
      int row = bm0 + wm + mi * 16 + quad * 4 + r;
      size_t base = (size_t)row * N + bn0 + wn + l16;
#pragma unroll
      for (int ni = 0; ni < 4; ++ni)
        y[base + ni * 16] = acc[mi][ni][r] + bv[ni];
    }
  }
}

// ---------------- flash attention (32x32 MFMA, ring-3, counted vmcnt) ------
// GRID: blockIdx.x = bh (B*H) -> id%8 = bh%8 keeps each head's K/V on one
// XCD's L2. blockIdx.y = q-tile (128 q / block, 4 waves x 32 q).
// Ring-3 over 64-key tiles (K 64x64 + V 64x64 bf16 = 16 KB/buf, 48 KB total
// -> 3 blocks/CU = 12 waves/CU). Per iter: stage(t+2) [4 gload16/thread] ->
// compute(t) -> vmcnt(4) [t+1 landed; t+2 in flight across barrier] -> sbar.
__global__ __launch_bounds__(256, 3) void flash_kernel(
    const unsigned short* __restrict__ qp,
    const unsigned short* __restrict__ kh,
    const unsigned short* __restrict__ vt,
    unsigned short* __restrict__ attn) {
  __shared__ __align__(16) unsigned short S_[24576];  // 48KB: 3 x (K4096|V4096)
  const int tid = threadIdx.x, wave = tid >> 6, lane = tid & 63;
  const int l32 = lane & 31, hf = lane >> 5;
  const int bh = blockIdx.x, b = bh >> 4, hd = bh & 15;
  const int q0 = blockIdx.y * 128;
  const unsigned short* kbase = kh + (size_t)bh * LL * HD;
  const unsigned short* vbase = vt + (size_t)bh * HD * LL;

  // Q fragments: direct load (rope + scale already applied by gemm_qkv)
  const int qrow = q0 + wave * 32 + l32;
  v8s qf[4];
  {
    const unsigned short* qsrc = qp + ((size_t)(b * LL + qrow) * DD + hd * HD);
#pragma unroll
    for (int ks2 = 0; ks2 < 4; ++ks2)
      qf[ks2] = *(const v8s*)(qsrc + ks2 * 16 + hf * 8);
  }

  // per-thread staging sources. LDS entry id*8 shorts holds (row=id>>3,
  // slot=id&7); slot s carries global chunk c = s ^ (row&7) (inverse-swizzled
  // source, m173). K row = key-in-tile (advance 64*HD/tile); V row = d
  // (advance 64 keys/tile within row).
  const int r0 = tid >> 3, s0 = tid & 7;
  const int r1 = (256 + tid) >> 3;
  const unsigned short* kS0 = kbase + (size_t)r0 * HD + (s0 ^ (r0 & 7)) * 8;
  const unsigned short* kS1 = kbase + (size_t)r1 * HD + (s0 ^ (r1 & 7)) * 8;
  const unsigned short* vS0 = vbase + (size_t)r0 * LL + (s0 ^ (r0 & 7)) * 8;
  const unsigned short* vS1 = vbase + (size_t)r1 * LL + (s0 ^ (r1 & 7)) * 8;

  v16f o0, o1;
#pragma unroll
  for (int i = 0; i < 16; ++i) { o0[i] = 0.0f; o1[i] = 0.0f; }
  float ls = 0.0f;

  auto stage = [&](int q, int t) {
    unsigned short* Kb = &S_[q * 8192];
    unsigned short* Vb = &S_[q * 8192 + 4096];
    gload16(kS0 + (size_t)t * 4096, &Kb[tid * 8]);
    gload16(kS1 + (size_t)t * 4096, &Kb[(256 + tid) * 8]);
    gload16(vS0 + t * 64, &Vb[tid * 8]);
    gload16(vS1 + t * 64, &Vb[(256 + tid) * 8]);
  };

  auto compute = [&](int q) {
    const unsigned short* Ks = &S_[q * 8192];
    const unsigned short* Vs = &S_[q * 8192 + 4096];
#pragma unroll
    for (int g = 0; g < 2; ++g) {   // 32-key groups
      v16f sc;
#pragma unroll
      for (int i = 0; i < 16; ++i) sc[i] = 0.0f;
#pragma unroll
      for (int ks2 = 0; ks2 < 4; ++ks2) {
        int row = g * 32 + l32;
        int slot = (ks2 * 2 + hf) ^ (row & 7);
        v8s kf = *(const v8s*)&Ks[row * 64 + slot * 8];
        sc = __builtin_amdgcn_mfma_f32_32x32x16_bf16(kf, qf[ks2], sc, 0, 0, 0);
      }
      v16f e;
#pragma unroll
      for (int i = 0; i < 16; ++i) e[i] = EXP2(sc[i]);
      float t0 = (e[0] + e[1]) + (e[2] + e[3]);
      float t1 = (e[4] + e[5]) + (e[6] + e[7]);
      float t2 = (e[8] + e[9]) + (e[10] + e[11]);
      float t3 = (e[12] + e[13]) + (e[14] + e[15]);
      ls += (t0 + t1) + (t2 + t3);
#pragma unroll
      for (int k2 = 0; k2 < 2; ++k2) {
        union { v8s v; unsigned int u[4]; } pb;
#pragma unroll
        for (int a = 0; a < 4; ++a)
          pb.u[a] = pk2(e[8 * k2 + 2 * a], e[8 * k2 + 2 * a + 1]);
        int k16 = g * 2 + k2;                 // 16-key slice in [0,4)
        int slotv = (k16 * 2 + hf) ^ (l32 & 7);
        v8s vf0 = *(const v8s*)&Vs[l32 * 64 + slotv * 8];
        v8s vf1 = *(const v8s*)&Vs[(32 + l32) * 64 + slotv * 8];
        o0 = __builtin_amdgcn_mfma_f32_32x32x16_bf16(vf0, pb.v, o0, 0, 0, 0);
        o1 = __builtin_amdgcn_mfma_f32_32x32x16_bf16(vf1, pb.v, o1, 0, 0, 0);
      }
    }
  };

  const int nt = LL / 64;   // 32 key-tiles
  stage(0, 0);
  stage(1, 1);
  VM_WAIT4;                 // tile 0 landed (Q loads retired too; tile 1 in flight)
  SBAR;
  int cur = 0, s2 = 2;
#pragma unroll 1
  for (int t = 0; t < nt - 2; ++t) {
    stage(s2, t + 2);       // 8 outstanding
    compute(cur);           // tile t
    VM_WAIT4;               // tile t+1 landed; t+2 stays in flight
    SBAR;
    cur = (cur == 2) ? 0 : cur + 1;
    s2 = (s2 == 2) ? 0 : s2 + 1;
  }
  compute(cur);             // tile nt-2 (buf 0)
  VM_WAIT0;                 // tile nt-1 landed
  SBAR;
  cur = (cur == 2) ? 0 : cur + 1;
  compute(cur);             // tile nt-1 (buf 1)

  ls += __shfl_xor(ls, 32);
  float inv = 1.0f / ls;

  // epilogue: O' (d x q) -> LDS buf0 (quiescent: last buf0 reads were tile
  // nt-2, fenced by the final SBAR; tile nt-1 readers touch buf1 only).
  unsigned short* Wt = S_ + wave * 2048;   // 32 q-rows x 64 d shorts
#pragma unroll
  for (int dt = 0; dt < 2; ++dt)
#pragma unroll
    for (int r = 0; r < 16; ++r) {
      int dl = (r & 3) + 8 * (r >> 2) + 4 * hf;   // d within 32
      int d = dt * 32 + dl;
      int chunk = d >> 3, offw = d & 7;
      int slot = chunk ^ (l32 & 7);
      float val = (dt == 0) ? o0[r] : o1[r];
      Wt[l32 * 64 + slot * 8 + offw] = f2b(val * inv);
    }
#pragma unroll
  for (int i = 0; i < 4; ++i) {
    int qr = lane >> 1;
    int chunk = (lane & 1) * 4 + i;
    int slot = chunk ^ (qr & 7);
    v8s dv = *(const v8s*)&Wt[qr * 64 + slot * 8];
    int token = q0 + wave * 32 + qr;
    *(v8s*)(attn + ((size_t)(b * LL + token) * DD) + hd * HD + chunk * 8) = dv;
  }
}

extern "C" void kernel_launch(void* const* d_in, const int* in_sizes, int n_in,
                              void* d_out, int out_size, void* d_ws, size_t ws_size,
                              hipStream_t stream) {
  const float* q  = (const float*)d_in[0];
  const float* k  = (const float*)d_in[1];
  const float* v  = (const float*)d_in[2];
  const float* wq = (const float*)d_in[3];
  const float* bq = (const float*)d_in[4];
  const float* wk = (const float*)d_in[5];
  const float* bk = (const float*)d_in[6];
  const float* wv = (const float*)d_in[7];
  const float* bv = (const float*)d_in[8];
  const float* wo = (const float*)d_in[9];
  const float* bo = (const float*)d_in[10];
  float* out = (float*)d_out;

  size_t off = 0;
  char* wsb = (char*)d_ws;
  auto take = [&](size_t n) { void* p = wsb + off; off += n; return p; };
  const size_t SZT = (size_t)BB * LL * DD * 2;  // 8 MB bf16 tensor
  const size_t SZW = (size_t)DD * DD * 2;       // 2 MB bf16 weight
  unsigned short* qb   = (unsigned short*)take(SZT);
  unsigned short* kb   = (unsigned short*)take(SZT);
  unsigned short* vb   = (unsigned short*)take(SZT);
  unsigned short* wqb  = (unsigned short*)take(SZW);
  unsigned short* wkb  = (unsigned short*)take(SZW);
  unsigned short* wvb  = (unsigned short*)take(SZW);
  unsigned short* wob  = (unsigned short*)take(SZW);
  unsigned short* qp   = (unsigned short*)take(SZT);
  unsigned short* khh  = (unsigned short*)take(SZT);
  unsigned short* vtt  = (unsigned short*)take(SZT);
  unsigned short* attn = (unsigned short*)take(SZT);
  float* ctab = (float*)take((size_t)LL * 32 * 4);
  float* stab = (float*)take((size_t)LL * 32 * 4);

  CastArgs ca;
  ca.s[0] = q;  ca.s[1] = k;  ca.s[2] = v;  ca.s[3] = wq;
  ca.s[4] = wk; ca.s[5] = wv; ca.s[6] = wo;
  ca.d[0] = qb;  ca.d[1] = kb;  ca.d[2] = vb;  ca.d[3] = wqb;
  ca.d[4] = wkb; ca.d[5] = wvb; ca.d[6] = wob;
  ca.ct = ctab; ca.st = stab;
  cast_all<<<dim3(1024, 1, 17), 256, 0, stream>>>(ca);

  // grids: x carries the XCD-keying (shared-operand) coordinate
  gemm_qkv<<<dim3(BB * LL / 128, DD / 128, 3), 256, 0, stream>>>(
      qb, kb, vb, wqb, wkb, wvb, bq, bk, bv, qp, khh, vtt, ctab, stab);

  flash_kernel<<<dim3(BB * NH, LL / 128), 256, 0, stream>>>(
      qp, khh, vtt, attn);

  gemm_out<<<dim3(BB * LL / 128, DD / 128, 1), 256, 0, stream>>>(attn, wob, bo, out);
}

// Round 6
// 210.250 us; speedup vs baseline: 1.0076x; 1.0076x over previous
//
#include <hip/hip_runtime.h>
#include <hip/hip_bf16.h>
#include <math.h>

// Problem constants: B=2, L=2048, D=1024, H=16, Hd=64
#define BB 2
#define LL 2048
#define DD 1024
#define NH 16
#define HD 64

typedef short v8s __attribute__((ext_vector_type(8)));   // 8 bf16 (4 VGPRs)
typedef float v4f __attribute__((ext_vector_type(4)));   // 4 fp32 acc
typedef float v16f __attribute__((ext_vector_type(16))); // 16 fp32 acc (32x32)

__device__ __forceinline__ float b2f(unsigned short b) {
  union { unsigned int u; float f; } c; c.u = ((unsigned int)b) << 16; return c.f;
}
__device__ __forceinline__ unsigned short f2b(float x) {
  union { float f; unsigned int u; } c; c.f = x;
  unsigned int u = c.u;
  u += 0x7fffu + ((u >> 16) & 1u);   // RNE
  return (unsigned short)(u >> 16);
}
__device__ __forceinline__ unsigned int asu(float x) {
  union { float f; unsigned int u; } c; c.f = x; return c.u;
}
// pack hi16(lo),hi16(hi) -> one u32 (bf16 RTZ x2) via v_perm_b32
__device__ __forceinline__ unsigned int pk2(float lo, float hi) {
  return __builtin_amdgcn_perm(asu(hi), asu(lo), 0x07060302u);
}

// exp2 (q pre-scaled by 0.125*log2e so softmax uses 2^x)
#if defined(__has_builtin)
#if __has_builtin(__builtin_amdgcn_exp2f)
#define EXP2(x) __builtin_amdgcn_exp2f(x)
#else
#define EXP2(x) __expf((x) * 0.69314718056f)
#endif
#else
#define EXP2(x) __expf((x) * 0.69314718056f)
#endif

// async global->LDS, 16B per lane. LDS dest must be lane-contiguous (m104/m108).
__device__ __forceinline__ void gload16(const void* g, void* l) {
  __builtin_amdgcn_global_load_lds(
      (const __attribute__((address_space(1))) void*)g,
      (__attribute__((address_space(3))) void*)l, 16, 0, 0);
}

// counted vmcnt waits (T4): asm volatile + memory clobber orders all memory
// ops; sched_barrier(0) after pins the schedule (rule #18).
#define VM_WAIT4 do { asm volatile("s_waitcnt vmcnt(4)" ::: "memory"); \
                      __builtin_amdgcn_sched_barrier(0); } while (0)
#define VM_WAIT0 do { asm volatile("s_waitcnt vmcnt(0)" ::: "memory"); \
                      __builtin_amdgcn_sched_barrier(0); } while (0)
#define SBAR     do { __builtin_amdgcn_s_barrier(); \
                      __builtin_amdgcn_sched_barrier(0); } while (0)

// ------ fused cast fp32->bf16 (z=0..15) + RoPE tables (z=16) ---------------
struct CastArgs { const float* s[7]; unsigned short* d[7]; float* ct; float* st; };
__global__ void cast_all(CastArgs a) {
  int z = blockIdx.z;
  if (z == 16) {                            // freqs: 2048*32 entries
    if (blockIdx.x >= 256) return;
    int id = blockIdx.x * blockDim.x + threadIdx.x;
    int t = id >> 5, i = id & 31;
    float inv = powf(10000.0f, -(float)(2 * i) / 64.0f);
    float ang = (float)t * inv;
    a.ct[id] = cosf(ang);
    a.st[id] = sinf(ang);
    return;
  }
  int t = (z < 12) ? (z >> 2) : (z - 9);    // q,k,v get 4 segs; weights 1 each
  int off = (z < 12) ? ((z & 3) << 18) : 0; // 262144 float4-groups per seg
  int i = off + blockIdx.x * blockDim.x + threadIdx.x;
  float4 v = ((const float4*)a.s[t])[i];
  ushort4 o;
  o.x = f2b(v.x); o.y = f2b(v.y); o.z = f2b(v.z); o.w = f2b(v.w);
  ((ushort4*)a.d[t])[i] = o;
}

// -------------- ring-3 GEMM core (128x128 tile, BK=32, counted vmcnt) ------
// LDS: 3 bufs x (A 128x32 + B 128x32) bf16 = 48 KB -> 3 blocks/CU.
// Schedule per iter t: stage tile t+2 (4 gload16) -> compute tile t (8
// ds_read_b128 + 16 MFMA) -> vmcnt(4) [tile t+1 landed, t+2 still IN FLIGHT
// across the barrier] -> s_barrier. Loads never drain to 0 in steady state.
__device__ __forceinline__ size_t ring_src_off(int id, int row0, int Kd) {
  int sr = id >> 3, slot = id & 7;
  int g = slot ^ (sr & 7);
  int r = (sr << 1) | (g >> 2), c = g & 3;
  return (size_t)(row0 + r) * Kd + c * 8;
}
__device__ __forceinline__ int ring_frag_off(int row, int quad) {
  int sr = row >> 1;
  int slot = (((row & 1) << 2) | quad) ^ (sr & 7);
  return sr * 64 + slot * 8;
}

// LDS_ layout: A bufs at [q*4096], B bufs at [12288 + q*4096]  (shorts)
__device__ __forceinline__ void ring_gemm_core(
    const unsigned short* __restrict__ X, const unsigned short* __restrict__ W,
    unsigned short* LDS_, int bm0, int bn0, v4f acc[4][4]) {
  const int K = DD;
  const int tid = threadIdx.x;
  const int lane = tid & 63, wave = tid >> 6;
  const int quad = lane >> 4, l16 = lane & 15;
  const int wm = (wave >> 1) * 64, wn = (wave & 1) * 64;

  // per-thread staging sources (advance by kofs per tile)
  const unsigned short* aS0 = X + ring_src_off(tid, bm0, K);
  const unsigned short* aS1 = X + ring_src_off(256 + tid, bm0, K);
  const unsigned short* bS0 = W + ring_src_off(tid, bn0, K);
  const unsigned short* bS1 = W + ring_src_off(256 + tid, bn0, K);

  // per-lane fragment LDS offsets (shorts)
  int aoff[4], boff[4];
#pragma unroll
  for (int i = 0; i < 4; ++i) {
    aoff[i] = ring_frag_off(wm + i * 16 + l16, quad);
    boff[i] = ring_frag_off(wn + i * 16 + l16, quad);
  }

  auto stage = [&](int q, int kofs) {
    unsigned short* Ab = &LDS_[q * 4096];
    unsigned short* Bb = &LDS_[12288 + q * 4096];
    gload16(aS0 + kofs, &Ab[tid * 8]);
    gload16(aS1 + kofs, &Ab[(256 + tid) * 8]);
    gload16(bS0 + kofs, &Bb[tid * 8]);
    gload16(bS1 + kofs, &Bb[(256 + tid) * 8]);
  };
  auto compute = [&](int q) {
    const unsigned short* Ab = &LDS_[q * 4096];
    const unsigned short* Bb = &LDS_[12288 + q * 4096];
    v8s a[4], b[4];
#pragma unroll
    for (int i = 0; i < 4; ++i) {
      a[i] = *(const v8s*)&Ab[aoff[i]];
      b[i] = *(const v8s*)&Bb[boff[i]];
    }
#pragma unroll
    for (int mi = 0; mi < 4; ++mi)
#pragma unroll
      for (int ni = 0; ni < 4; ++ni)
        acc[mi][ni] = __builtin_amdgcn_mfma_f32_16x16x32_bf16(a[mi], b[ni], acc[mi][ni], 0, 0, 0);
  };

  const int nt = K / 32;   // 32 k-tiles
  stage(0, 0);
  stage(1, 32);
  VM_WAIT4;                // tile 0 landed (tile 1's 4 loads in flight)
  SBAR;
  int cur = 0, s2 = 2, kofs = 64;
#pragma unroll 1
  for (int t = 0; t < nt - 2; ++t) {
    stage(s2, kofs);       // tile t+2 -> 8 outstanding
    compute(cur);          // tile t
    VM_WAIT4;              // tile t+1 landed; t+2 stays in flight
    SBAR;
    cur = (cur == 2) ? 0 : cur + 1;
    s2 = (s2 == 2) ? 0 : s2 + 1;
    kofs += 32;
  }
  compute(cur);            // tile nt-2
  VM_WAIT0;                // tile nt-1 landed
  SBAR;
  cur = (cur == 2) ? 0 : cur + 1;
  compute(cur);            // tile nt-1 (no trailing barrier needed)
}

// ---------------- QKV GEMM with fused RoPE -------------------------------
// z=0 (Q): rope + 0.125*log2e scale fused in epilogue, write qp [B,L,D].
// z=1 (K): rope fused in epilogue, write khh [B,H,L,Hd] directly.
// z=2 (V): transpose in LDS -> vt [B,H,Hd,L_perm].
__global__ __launch_bounds__(256, 3) void gemm_qkv(
    const unsigned short* __restrict__ qb, const unsigned short* __restrict__ kb,
    const unsigned short* __restrict__ vb,
    const unsigned short* __restrict__ wqb, const unsigned short* __restrict__ wkb,
    const unsigned short* __restrict__ wvb,
    const float* __restrict__ bq, const float* __restrict__ bk,
    const float* __restrict__ bv_,
    unsigned short* __restrict__ qp, unsigned short* __restrict__ khh,
    unsigned short* __restrict__ vt,
    const float* __restrict__ ctab, const float* __restrict__ stab) {
  __shared__ __align__(16) unsigned short LDS_[24576];   // 48 KB ring
  const int z = blockIdx.z;
  const unsigned short* X = (z == 0) ? qb : (z == 1) ? kb : vb;
  const unsigned short* W = (z == 0) ? wqb : (z == 1) ? wkb : wvb;
  const float* bias = (z == 0) ? bq : (z == 1) ? bk : bv_;
  const int N = DD;
  const int tid = threadIdx.x;
  const int lane = tid & 63, wave = tid >> 6;
  const int quad = lane >> 4, l16 = lane & 15;
  const int bm0 = blockIdx.x * 128;     // XCD-keyed (id%8 = bm%8)
  const int bn0 = blockIdx.y * 128;
  const int wm = (wave >> 1) * 64, wn = (wave & 1) * 64;

  const v4f vzero = {0.f, 0.f, 0.f, 0.f};
  v4f acc[4][4];
#pragma unroll
  for (int i = 0; i < 4; ++i)
#pragma unroll
    for (int j = 0; j < 4; ++j) acc[i][j] = vzero;

  ring_gemm_core(X, W, LDS_, bm0, bn0, acc);

  float bv[4];
#pragma unroll
  for (int ni = 0; ni < 4; ++ni) bv[ni] = bias[bn0 + wn + ni * 16 + l16];

  if (z < 2) {
    // fused rope epilogue (Q: +softmax scale; K: direct to [B,H,L,Hd])
    const float scl = (z == 0) ? 0.18033688f : 1.0f;  // 0.125*log2(e) for Q
    const int h = (bn0 + wn) >> 6;                    // head (wave-uniform)
    const float sgn = (l16 & 1) ? 1.0f : -1.0f;
#pragma unroll
    for (int mi = 0; mi < 4; ++mi) {
#pragma unroll
      for (int r = 0; r < 4; ++r) {
        int row = bm0 + wm + mi * 16 + quad * 4 + r;
        int l = row & (LL - 1);
        int bidx = row >> 11;
        size_t baseq = (size_t)row * N + bn0 + wn + l16;
        size_t basek = ((size_t)(bidx * NH + h) * LL + l) * HD + l16;
#pragma unroll
        for (int ni = 0; ni < 4; ++ni) {
          int ii = (ni * 16 + l16) >> 1;              // freq index in [0,32)
          float c = ctab[l * 32 + ii], s = stab[l * 32 + ii];
          float v = acc[mi][ni][r] + bv[ni];
          float vp = __shfl_xor(v, 1);
          // even lane: v*c - vp*s ; odd lane: v*c + vp*s
          float o = (v * c + sgn * (vp * s)) * scl;
          if (z == 0) qp[baseq + ni * 16] = f2b(o);
          else        khh[basek + ni * 16] = f2b(o);
        }
      }
    }
  } else {
    // V: transpose in LDS (token bits 2,3 swapped -> flash key permutation),
    // then coalesced store to vt[B,H,Hd,L_perm]. T reuses the ring buffers;
    // barrier first so all waves' last-tile reads are done.
    __syncthreads();
    unsigned short* T = LDS_;          // 128x128 shorts = 32 KB (fits 48)
#pragma unroll
    for (int mi = 0; mi < 4; ++mi)
#pragma unroll
      for (int r = 0; r < 4; ++r) {
        int tl = wm + mi * 16 + quad * 4 + r;                 // token local
        int tlp = (tl & ~12) | ((tl & 4) << 1) | ((tl & 8) >> 1);
        int chunk = tlp >> 3, offw = tlp & 7;
#pragma unroll
        for (int ni = 0; ni < 4; ++ni) {
          int fl = wn + ni * 16 + l16;                        // feature local
          T[fl * 128 + ((chunk ^ (fl & 15)) * 8) + offw] =
              f2b(acc[mi][ni][r] + bv[ni]);
        }
      }
    __syncthreads();
    int fl = tid >> 1, half = tid & 1;
    int fg = bn0 + fl;
    int h2 = fg >> 6, d = fg & 63;
    int bidx = bm0 >> 11, l0 = bm0 & (LL - 1);
    unsigned short* dst =
        vt + (((size_t)(bidx * NH + h2) * HD + d) * LL) + l0 + half * 64;
#pragma unroll
    for (int i = 0; i < 8; ++i) {
      int chunk = half * 8 + i;
      int slot = chunk ^ (fl & 15);
      *(v8s*)(dst + i * 8) = *(const v8s*)&T[fl * 128 + slot * 8];
    }
  }
}

__global__ __launch_bounds__(256, 3) void gemm_out(
    const unsigned short* __restrict__ x, const unsigned short* __restrict__ w,
    const float* __restrict__ b, float* __restrict__ y) {
  __shared__ __align__(16) unsigned short LDS_[24576];   // 48 KB ring
  const int N = DD;
  const int tid = threadIdx.x;
  const int lane = tid & 63, wave = tid >> 6;
  const int quad = lane >> 4, l16 = lane & 15;
  const int bm0 = blockIdx.x * 128;
  const int bn0 = blockIdx.y * 128;
  const int wm = (wave >> 1) * 64, wn = (wave & 1) * 64;

  const v4f vzero = {0.f, 0.f, 0.f, 0.f};
  v4f acc[4][4];
#pragma unroll
  for (int i = 0; i < 4; ++i)
#pragma unroll
    for (int j = 0; j < 4; ++j) acc[i][j] = vzero;

  ring_gemm_core(x, w, LDS_, bm0, bn0, acc);

  float bv[4];
#pragma unroll
  for (int ni = 0; ni < 4; ++ni) bv[ni] = b[bn0 + wn + ni * 16 + l16];
#pragma unroll
  for (int mi = 0; mi < 4; ++mi) {
#pragma unroll
    for (int r = 0; r < 4; ++r) {
      int row = bm0 + wm + mi * 16 + quad * 4 + r;
      size_t base = (size_t)row * N + bn0 + wn + l16;
#pragma unroll
      for (int ni = 0; ni < 4; ++ni)
        y[base + ni * 16] = acc[mi][ni][r] + bv[ni];
    }
  }
}

// ---------------- flash attention (32x32 MFMA, ring-3, counted vmcnt) ------
// GRID: blockIdx.x = bh (B*H) -> id%8 = bh%8 keeps each head's K/V on one
// XCD's L2. blockIdx.y = q-tile (128 q / block, 4 waves x 32 q).
// Grid = 512 blocks -> 2 blocks/CU (grid-limited), so per-wave ILP is the
// lever: compute() batches BOTH 32-key groups -> two independent QK chains
// (sc0,sc1), V-frags prefetched before the QK cluster (LDS latency hides
// under MFMA), 32-wide exp2 burst, one 16-MFMA PV cluster (indep o0/o1
// chains). setprio(1) wraps MFMA clusters (T5).
__global__ __launch_bounds__(256, 2) void flash_kernel(
    const unsigned short* __restrict__ qp,
    const unsigned short* __restrict__ kh,
    const unsigned short* __restrict__ vt,
    unsigned short* __restrict__ attn) {
  __shared__ __align__(16) unsigned short S_[24576];  // 48KB: 3 x (K4096|V4096)
  const int tid = threadIdx.x, wave = tid >> 6, lane = tid & 63;
  const int l32 = lane & 31, hf = lane >> 5;
  const int bh = blockIdx.x, b = bh >> 4, hd = bh & 15;
  const int q0 = blockIdx.y * 128;
  const unsigned short* kbase = kh + (size_t)bh * LL * HD;
  const unsigned short* vbase = vt + (size_t)bh * HD * LL;

  // Q fragments: direct load (rope + scale already applied by gemm_qkv)
  const int qrow = q0 + wave * 32 + l32;
  v8s qf[4];
  {
    const unsigned short* qsrc = qp + ((size_t)(b * LL + qrow) * DD + hd * HD);
#pragma unroll
    for (int ks2 = 0; ks2 < 4; ++ks2)
      qf[ks2] = *(const v8s*)(qsrc + ks2 * 16 + hf * 8);
  }

  // per-thread staging sources (inverse-swizzled global source, m173)
  const int r0 = tid >> 3, s0 = tid & 7;
  const int r1 = (256 + tid) >> 3;
  const unsigned short* kS0 = kbase + (size_t)r0 * HD + (s0 ^ (r0 & 7)) * 8;
  const unsigned short* kS1 = kbase + (size_t)r1 * HD + (s0 ^ (r1 & 7)) * 8;
  const unsigned short* vS0 = vbase + (size_t)r0 * LL + (s0 ^ (r0 & 7)) * 8;
  const unsigned short* vS1 = vbase + (size_t)r1 * LL + (s0 ^ (r1 & 7)) * 8;

  v16f o0, o1;
#pragma unroll
  for (int i = 0; i < 16; ++i) { o0[i] = 0.0f; o1[i] = 0.0f; }
  float ls = 0.0f;

  auto stage = [&](int q, int t) {
    unsigned short* Kb = &S_[q * 8192];
    unsigned short* Vb = &S_[q * 8192 + 4096];
    gload16(kS0 + (size_t)t * 4096, &Kb[tid * 8]);
    gload16(kS1 + (size_t)t * 4096, &Kb[(256 + tid) * 8]);
    gload16(vS0 + t * 64, &Vb[tid * 8]);
    gload16(vS1 + t * 64, &Vb[(256 + tid) * 8]);
  };

  auto compute = [&](int q) {
    const unsigned short* Ks = &S_[q * 8192];
    const unsigned short* Vs = &S_[q * 8192 + 4096];
    const int row0 = l32, row1 = 32 + l32;
    // K fragments, both 32-key groups (8 ds_read_b128)
    v8s kf0[4], kf1[4];
#pragma unroll
    for (int ks2 = 0; ks2 < 4; ++ks2) {
      kf0[ks2] = *(const v8s*)&Ks[row0 * 64 + (((ks2 * 2 + hf) ^ (row0 & 7)) * 8)];
      kf1[ks2] = *(const v8s*)&Ks[row1 * 64 + (((ks2 * 2 + hf) ^ (row1 & 7)) * 8)];
    }
    // V fragments, all 4 16-key slices (8 ds_read_b128) — issued BEFORE the
    // QK MFMA cluster so their LDS latency hides under MFMA.
    v8s vfa[4], vfb[4];
#pragma unroll
    for (int k16 = 0; k16 < 4; ++k16) {
      int slotv = (k16 * 2 + hf) ^ (l32 & 7);
      vfa[k16] = *(const v8s*)&Vs[l32 * 64 + slotv * 8];
      vfb[k16] = *(const v8s*)&Vs[(32 + l32) * 64 + slotv * 8];
    }
    // QK: two INDEPENDENT accumulator chains, interleaved
    v16f sc0, sc1;
#pragma unroll
    for (int i = 0; i < 16; ++i) { sc0[i] = 0.0f; sc1[i] = 0.0f; }
    __builtin_amdgcn_s_setprio(1);
#pragma unroll
    for (int ks2 = 0; ks2 < 4; ++ks2) {
      sc0 = __builtin_amdgcn_mfma_f32_32x32x16_bf16(kf0[ks2], qf[ks2], sc0, 0, 0, 0);
      sc1 = __builtin_amdgcn_mfma_f32_32x32x16_bf16(kf1[ks2], qf[ks2], sc1, 0, 0, 0);
    }
    __builtin_amdgcn_s_setprio(0);
    // softmax (no-max, exp2), 32-wide trans burst
    v16f e0, e1;
#pragma unroll
    for (int i = 0; i < 16; ++i) e0[i] = EXP2(sc0[i]);
#pragma unroll
    for (int i = 0; i < 16; ++i) e1[i] = EXP2(sc1[i]);
    float s00 = (e0[0] + e0[1]) + (e0[2] + e0[3]);
    float s01 = (e0[4] + e0[5]) + (e0[6] + e0[7]);
    float s02 = (e0[8] + e0[9]) + (e0[10] + e0[11]);
    float s03 = (e0[12] + e0[13]) + (e0[14] + e0[15]);
    float s10 = (e1[0] + e1[1]) + (e1[2] + e1[3]);
    float s11 = (e1[4] + e1[5]) + (e1[6] + e1[7]);
    float s12 = (e1[8] + e1[9]) + (e1[10] + e1[11]);
    float s13 = (e1[12] + e1[13]) + (e1[14] + e1[15]);
    ls += ((s00 + s01) + (s02 + s03)) + ((s10 + s11) + (s12 + s13));
    // pack P -> bf16x2 (k16 slice order: g0k0, g0k1, g1k0, g1k1)
    union { v8s v; unsigned int u[4]; } pb0, pb1, pb2, pb3;
#pragma unroll
    for (int a = 0; a < 4; ++a) {
      pb0.u[a] = pk2(e0[2 * a], e0[2 * a + 1]);
      pb1.u[a] = pk2(e0[8 + 2 * a], e0[8 + 2 * a + 1]);
      pb2.u[a] = pk2(e1[2 * a], e1[2 * a + 1]);
      pb3.u[a] = pk2(e1[8 + 2 * a], e1[8 + 2 * a + 1]);
    }
    // PV: 16 MFMA, two independent chains (o0,o1) interleaved
    __builtin_amdgcn_s_setprio(1);
    o0 = __builtin_amdgcn_mfma_f32_32x32x16_bf16(vfa[0], pb0.v, o0, 0, 0, 0);
    o1 = __builtin_amdgcn_mfma_f32_32x32x16_bf16(vfb[0], pb0.v, o1, 0, 0, 0);
    o0 = __builtin_amdgcn_mfma_f32_32x32x16_bf16(vfa[1], pb1.v, o0, 0, 0, 0);
    o1 = __builtin_amdgcn_mfma_f32_32x32x16_bf16(vfb[1], pb1.v, o1, 0, 0, 0);
    o0 = __builtin_amdgcn_mfma_f32_32x32x16_bf16(vfa[2], pb2.v, o0, 0, 0, 0);
    o1 = __builtin_amdgcn_mfma_f32_32x32x16_bf16(vfb[2], pb2.v, o1, 0, 0, 0);
    o0 = __builtin_amdgcn_mfma_f32_32x32x16_bf16(vfa[3], pb3.v, o0, 0, 0, 0);
    o1 = __builtin_amdgcn_mfma_f32_32x32x16_bf16(vfb[3], pb3.v, o1, 0, 0, 0);
    __builtin_amdgcn_s_setprio(0);
  };

  const int nt = LL / 64;   // 32 key-tiles
  stage(0, 0);
  stage(1, 1);
  VM_WAIT4;                 // tile 0 landed; tile 1 in flight
  SBAR;
  int cur = 0, s2 = 2;
#pragma unroll 1
  for (int t = 0; t < nt - 2; ++t) {
    stage(s2, t + 2);       // 8 outstanding
    compute(cur);           // tile t
    VM_WAIT4;               // tile t+1 landed; t+2 stays in flight
    SBAR;
    cur = (cur == 2) ? 0 : cur + 1;
    s2 = (s2 == 2) ? 0 : s2 + 1;
  }
  compute(cur);             // tile nt-2 (buf 0)
  VM_WAIT0;                 // tile nt-1 landed
  SBAR;
  cur = (cur == 2) ? 0 : cur + 1;
  compute(cur);             // tile nt-1 (buf 1)

  ls += __shfl_xor(ls, 32);
  float inv = 1.0f / ls;

  // epilogue: O' (d x q) -> LDS buf0 (quiescent: last buf0 reads were tile
  // nt-2, fenced by the final SBAR; tile nt-1 readers touch buf1 only).
  unsigned short* Wt = S_ + wave * 2048;   // 32 q-rows x 64 d shorts
#pragma unroll
  for (int dt = 0; dt < 2; ++dt)
#pragma unroll
    for (int r = 0; r < 16; ++r) {
      int dl = (r & 3) + 8 * (r >> 2) + 4 * hf;   // d within 32
      int d = dt * 32 + dl;
      int chunk = d >> 3, offw = d & 7;
      int slot = chunk ^ (l32 & 7);
      float val = (dt == 0) ? o0[r] : o1[r];
      Wt[l32 * 64 + slot * 8 + offw] = f2b(val * inv);
    }
#pragma unroll
  for (int i = 0; i < 4; ++i) {
    int qr = lane >> 1;
    int chunk = (lane & 1) * 4 + i;
    int slot = chunk ^ (qr & 7);
    v8s dv = *(const v8s*)&Wt[qr * 64 + slot * 8];
    int token = q0 + wave * 32 + qr;
    *(v8s*)(attn + ((size_t)(b * LL + token) * DD) + hd * HD + chunk * 8) = dv;
  }
}

extern "C" void kernel_launch(void* const* d_in, const int* in_sizes, int n_in,
                              void* d_out, int out_size, void* d_ws, size_t ws_size,
                              hipStream_t stream) {
  const float* q  = (const float*)d_in[0];
  const float* k  = (const float*)d_in[1];
  const float* v  = (const float*)d_in[2];
  const float* wq = (const float*)d_in[3];
  const float* bq = (const float*)d_in[4];
  const float* wk = (const float*)d_in[5];
  const float* bk = (const float*)d_in[6];
  const float* wv = (const float*)d_in[7];
  const float* bv = (const float*)d_in[8];
  const float* wo = (const float*)d_in[9];
  const float* bo = (const float*)d_in[10];
  float* out = (float*)d_out;

  size_t off = 0;
  char* wsb = (char*)d_ws;
  auto take = [&](size_t n) { void* p = wsb + off; off += n; return p; };
  const size_t SZT = (size_t)BB * LL * DD * 2;  // 8 MB bf16 tensor
  const size_t SZW = (size_t)DD * DD * 2;       // 2 MB bf16 weight
  unsigned short* qb   = (unsigned short*)take(SZT);
  unsigned short* kb   = (unsigned short*)take(SZT);
  unsigned short* vb   = (unsigned short*)take(SZT);
  unsigned short* wqb  = (unsigned short*)take(SZW);
  unsigned short* wkb  = (unsigned short*)take(SZW);
  unsigned short* wvb  = (unsigned short*)take(SZW);
  unsigned short* wob  = (unsigned short*)take(SZW);
  unsigned short* qp   = (unsigned short*)take(SZT);
  unsigned short* khh  = (unsigned short*)take(SZT);
  unsigned short* vtt  = (unsigned short*)take(SZT);
  unsigned short* attn = (unsigned short*)take(SZT);
  float* ctab = (float*)take((size_t)LL * 32 * 4);
  float* stab = (float*)take((size_t)LL * 32 * 4);

  CastArgs ca;
  ca.s[0] = q;  ca.s[1] = k;  ca.s[2] = v;  ca.s[3] = wq;
  ca.s[4] = wk; ca.s[5] = wv; ca.s[6] = wo;
  ca.d[0] = qb;  ca.d[1] = kb;  ca.d[2] = vb;  ca.d[3] = wqb;
  ca.d[4] = wkb; ca.d[5] = wvb; ca.d[6] = wob;
  ca.ct = ctab; ca.st = stab;
  cast_all<<<dim3(1024, 1, 17), 256, 0, stream>>>(ca);

  // grids: x carries the XCD-keying (shared-operand) coordinate
  gemm_qkv<<<dim3(BB * LL / 128, DD / 128, 3), 256, 0, stream>>>(
      qb, kb, vb, wqb, wkb, wvb, bq, bk, bv, qp, khh, vtt, ctab, stab);

  flash_kernel<<<dim3(BB * NH, LL / 128), 256, 0, stream>>>(
      qp, khh, vtt, attn);

  gemm_out<<<dim3(BB * LL / 128, DD / 128, 1), 256, 0, stream>>>(attn, wob, bo, out);
}